// Round 6
// baseline (289.145 us; speedup 1.0000x reference)
//
#include <hip/hip_runtime.h>
#include <stdint.h>
#include <stddef.h>

#define NN 8192
#define DD 256
#define HH 128

typedef short bf16x8  __attribute__((ext_vector_type(8)));
typedef float f32x4   __attribute__((ext_vector_type(4)));
typedef float f32x16  __attribute__((ext_vector_type(16)));
typedef int   i32x4   __attribute__((ext_vector_type(4)));

// f32 -> bf16 RNE
static __device__ __forceinline__ short f2bf(float x){
  unsigned u = __float_as_uint(x);
  u = (u + 0x7FFFu + ((u >> 16) & 1u)) >> 16;
  return (short)(unsigned short)u;
}
static __device__ __forceinline__ bf16x8 cvt8(const float* p){
  f32x4 a = *(const f32x4*)p;
  f32x4 b = *(const f32x4*)(p + 4);
  bf16x8 o;
  o[0]=f2bf(a[0]); o[1]=f2bf(a[1]); o[2]=f2bf(a[2]); o[3]=f2bf(a[3]);
  o[4]=f2bf(b[0]); o[5]=f2bf(b[1]); o[6]=f2bf(b[2]); o[7]=f2bf(b[3]);
  return o;
}
static __device__ __forceinline__ bf16x8 ld16(const void* p){
  i32x4 v = *(const i32x4*)p;
  return __builtin_bit_cast(bf16x8, v);
}

// ---------- features [N][D] f32 -> ft_frag: MFMA B-fragment-ready layout ----------
__global__ __launch_bounds__(256) void k_ftfrag(const float* __restrict__ f,
                                                unsigned short* __restrict__ ftf){
  int t = threadIdx.x;
  int fr = blockIdx.x * 4 + (t >> 6);   // frag id 0..4095
  int l  = t & 63;
  int jt = fr >> 3, dt = fr & 7;
  int j = jt * 16 + (l >> 5) * 8, d = dt * 32 + (l & 31);
  bf16x8 o;
  #pragma unroll
  for (int e = 0; e < 8; ++e) o[e] = f2bf(f[(size_t)(j + e) * DD + d]);
  *(bf16x8*)(ftf + (size_t)fr * 512 + l * 8) = o;
}

// ---------- projections ----------
// Kn: row-major [i][128] bf16. Qn: B-fragment-ready (see k_attn).
__global__ __launch_bounds__(256) void k_proj(const float* __restrict__ f,
                                              const float* __restrict__ Wq,
                                              const float* __restrict__ Wk,
                                              unsigned short* __restrict__ Qnf,
                                              unsigned short* __restrict__ Kn){
  int t = threadIdx.x, wave = t >> 6, l = t & 63;
  int i0 = blockIdx.x * 64 + wave * 16;
  int lr = l & 15, lk = l >> 4;
  bf16x8 ka[8];
  #pragma unroll
  for (int ks = 0; ks < 8; ++ks)
    ka[ks] = cvt8(f + (size_t)(i0 + lr) * DD + ks * 32 + lk * 8);
  for (int pj = 0; pj < 2; ++pj){
    const float* W = pj ? Wk : Wq;
    f32x4 acc[8];
    #pragma unroll
    for (int n = 0; n < 8; ++n) acc[n] = (f32x4){0.f,0.f,0.f,0.f};
    for (int ks = 0; ks < 8; ++ks)
      #pragma unroll
      for (int n = 0; n < 8; ++n){
        bf16x8 bb = cvt8(W + (size_t)(n * 16 + lr) * DD + ks * 32 + lk * 8);
        acc[n] = __builtin_amdgcn_mfma_f32_16x16x32_bf16(ka[ks], bb, acc[n], 0, 0, 0);
      }
    #pragma unroll
    for (int r = 0; r < 4; ++r){
      float n2 = 0.f;
      #pragma unroll
      for (int n = 0; n < 8; ++n){ float v = acc[n][r]; n2 += v * v; }
      n2 += __shfl_xor(n2, 1); n2 += __shfl_xor(n2, 2);
      n2 += __shfl_xor(n2, 4); n2 += __shfl_xor(n2, 8);
      float s = 1.f / fmaxf(sqrtf(n2), 1e-4f);   // torch cosine eps
      int row = i0 + lk * 4 + r;
      #pragma unroll
      for (int n = 0; n < 8; ++n){
        short v = f2bf(acc[n][r] * s);
        if (pj){
          Kn[(size_t)row * HH + n * 16 + lr] = (unsigned short)v;
        } else {
          size_t off = ((size_t)(row >> 5) * 8 + n) * 512
                     + ((row & 31) + 32 * (lr >> 3)) * 8 + (lr & 7);
          Qnf[off] = (unsigned short)v;
        }
      }
    }
  }
}

// ---------- adj (256MB int) -> bitmask (8MB): pure stream, PLAIN loads ----------
// wave gw: row = gw>>3, 1024-col chunk = gw&7; 16 iters x 256B coalesced.
__global__ __launch_bounds__(256) void k_pack(const int* __restrict__ adj,
                                              unsigned* __restrict__ bits){
  int wave = threadIdx.x >> 6, l = threadIdx.x & 63;
  int gw = blockIdx.x * 4 + wave;            // 65536 waves
  int row = gw >> 3, chunk = gw & 7;
  const int* ap = adj + (size_t)row * NN + chunk * 1024 + l;
  unsigned long long* bp = (unsigned long long*)(bits + (size_t)row * 256 + chunk * 32);
  #pragma unroll
  for (int it = 0; it < 16; ++it){
    int v = ap[it * 64];
    unsigned long long m = __ballot(v > 0);
    if (l == 0) bp[it] = m;
  }
}

// ---------- fused masked-softmax attention (v6) ----------
// 512 blocks = 128 ib x 4 js. 4 waves. Per 64-j step:
//  QK^T (32x32x16, frag loads from L2) -> mask from L3-resident bitmask
//  (16 broadcast dwords/step) -> exp -> P via 8KB swizzled LDS -> PV.
//  NO HBM traffic in the loop; no vmcnt(0)-drain of long-latency loads.
__global__ __launch_bounds__(256, 2) void k_attn(
      const unsigned* __restrict__ bits,
      const unsigned short* __restrict__ Qnf, const unsigned short* __restrict__ Kn,
      const unsigned short* __restrict__ ftf,
      float* __restrict__ num_p, float* __restrict__ den_p){
  __shared__ __attribute__((aligned(16))) char p_lds[8192];  // P [64i][64j] bf16 swizzled
  int t = threadIdx.x, wave = t >> 6, l = t & 63;
  int lc = l & 31, h = l >> 5;
  int ig = wave >> 1, jg = wave & 1, wq = wave;
  int ib = blockIdx.x >> 2, js = blockIdx.x & 3;
  int i0 = ib * 64;
  int jbase = js * 2048;

  // Kn A-frags: lane holds Kn[i0+ig*32+lc][hs*16 + h*8 + e]
  bf16x8 kb[8];
  { const unsigned short* kp = Kn + (size_t)(i0 + ig * 32 + lc) * HH + h * 8;
    #pragma unroll
    for (int hs = 0; hs < 8; ++hs) kb[hs] = ld16(kp + hs * 16); }

  f32x16 pv00, pv01, pv10, pv11;
  #pragma unroll
  for (int e = 0; e < 16; ++e){ pv00[e]=0.f; pv01[e]=0.f; pv10[e]=0.f; pv11[e]=0.f; }
  float dacc[16];
  #pragma unroll
  for (int r = 0; r < 16; ++r) dacc[r] = 0.f;

  for (int s = 0; s < 32; ++s){
    int j0 = jbase + s * 64;

    // Qn frag loads (L2)
    bf16x8 qv[8];
    { const unsigned short* qb = Qnf + ((size_t)((j0 + jg * 32) >> 5) * 8) * 512 + (size_t)l * 8;
      #pragma unroll
      for (int hs = 0; hs < 8; ++hs) qv[hs] = ld16(qb + hs * 512); }

    // mask words (L3-resident bits; 32-lane broadcast per load)
    int w0 = (j0 >> 5) + jg;
    unsigned mw[16];
    #pragma unroll
    for (int r = 0; r < 16; ++r){
      int row = i0 + ig * 32 + (r & 3) + 8 * (r >> 2) + 4 * h;
      mw[r] = bits[(size_t)row * 256 + w0];
    }

    // ft frag loads (L2)
    bf16x8 bv[8];
    { const unsigned short* fb = ftf + ((size_t)(j0 >> 4) * 8 + wq * 2) * 512 + (size_t)l * 8;
      #pragma unroll
      for (int ks = 0; ks < 4; ++ks){
        bv[ks * 2]     = ld16(fb + ks * 4096);
        bv[ks * 2 + 1] = ld16(fb + ks * 4096 + 512); } }

    // QK^T: st[r] = S[i0+ig*32 + (r&3)+8*(r>>2)+4h][j0 + jg*32 + lc]
    f32x16 st;
    #pragma unroll
    for (int e = 0; e < 16; ++e) st[e] = 0.f;
    #pragma unroll
    for (int hs = 0; hs < 8; ++hs)
      st = __builtin_amdgcn_mfma_f32_32x32x16_bf16(kb[hs], qv[hs], st, 0, 0, 0);

    // mask -> exp -> P to swizzled LDS
    #pragma unroll
    for (int r = 0; r < 16; ++r){
      int row = ig * 32 + (r & 3) + 8 * (r >> 2) + 4 * h;
      float wv = ((mw[r] >> lc) & 1u) ? __expf(st[r]) : 0.f;  // |s|<=1: exp safe
      dacc[r] += wv;
      int byo = row * 128 + (((jg * 32 + lc) * 2) ^ ((row & 7) << 4));
      *(unsigned short*)(p_lds + byo) = (unsigned short)f2bf(wv);
    }
    __syncthreads();                     // P visible

    // PV: pvXY += P(full 64j) * ft(d-quarter wq)
    #pragma unroll
    for (int ks = 0; ks < 4; ++ks){
      int ko = (ks * 32 + h * 16) ^ ((lc & 7) << 4);
      bf16x8 pa0 = ld16(p_lds + lc * 128 + ko);
      bf16x8 pa1 = ld16(p_lds + (32 + lc) * 128 + ko);
      pv00 = __builtin_amdgcn_mfma_f32_32x32x16_bf16(pa0, bv[ks*2],   pv00, 0,0,0);
      pv01 = __builtin_amdgcn_mfma_f32_32x32x16_bf16(pa0, bv[ks*2+1], pv01, 0,0,0);
      pv10 = __builtin_amdgcn_mfma_f32_32x32x16_bf16(pa1, bv[ks*2],   pv10, 0,0,0);
      pv11 = __builtin_amdgcn_mfma_f32_32x32x16_bf16(pa1, bv[ks*2+1], pv11, 0,0,0);
    }
    __syncthreads();                     // PV readers done; p_lds reusable
  }

  // den partials: reduce over j-lanes, store per (js,jg)
  #pragma unroll
  for (int r = 0; r < 16; ++r){
    float v = dacc[r];
    v += __shfl_xor(v, 1); v += __shfl_xor(v, 2); v += __shfl_xor(v, 4);
    v += __shfl_xor(v, 8); v += __shfl_xor(v, 16);
    if (lc == 0){
      int i = i0 + ig * 32 + (r & 3) + 8 * (r >> 2) + 4 * h;
      den_p[(size_t)(js * 2 + jg) * NN + i] = v;
    }
  }
  // num partials: plain coalesced stores (per-js region)
  float* np = num_p + (size_t)js * NN * DD;
  #pragma unroll
  for (int r = 0; r < 16; ++r){
    int i = i0 + (r & 3) + 8 * (r >> 2) + 4 * h;
    int d = wq * 64 + lc;
    np[(size_t)i * DD + d]             = pv00[r];
    np[(size_t)i * DD + d + 32]        = pv01[r];
    np[(size_t)(i + 32) * DD + d]      = pv10[r];
    np[(size_t)(i + 32) * DD + d + 32] = pv11[r];
  }
}

// ---------- finalize: sum partials; out = den>0 ? 0.5*num/den + 0.5*f : f ----------
__global__ __launch_bounds__(256) void k_final(const float* __restrict__ num_p,
                                               const float* __restrict__ den_p,
                                               const float* __restrict__ f,
                                               float* __restrict__ out){
  int gid = blockIdx.x * 256 + threadIdx.x;
  int i = gid >> 6;
  f32x4 nv = (f32x4){0.f,0.f,0.f,0.f};
  float dv = 0.f;
  #pragma unroll
  for (int s = 0; s < 4; ++s)
    nv += *(const f32x4*)(num_p + (size_t)s * NN * DD + (size_t)gid * 4);
  #pragma unroll
  for (int s = 0; s < 8; ++s)
    dv += den_p[(size_t)s * NN + i];
  f32x4 fv = *(const f32x4*)(f + (size_t)gid * 4);
  f32x4 o;
  if (dv > 0.f){
    float inv = 0.5f / dv;
    o = nv * inv + fv * 0.5f;
  } else {
    o = fv;   // no-neighbor row keeps features
  }
  *(f32x4*)(out + (size_t)gid * 4) = o;
}

extern "C" void kernel_launch(void* const* d_in, const int* in_sizes, int n_in,
                              void* d_out, int out_size, void* d_ws, size_t ws_size,
                              hipStream_t stream){
  (void)in_sizes; (void)n_in; (void)out_size;
  const float* feat = (const float*)d_in[0];
  const int*   adj  = (const int*)d_in[1];
  const float* Wq   = (const float*)d_in[2];
  const float* Wk   = (const float*)d_in[3];
  float* out = (float*)d_out;
  char* ws = (char*)d_ws;
  unsigned short* Qnf  = (unsigned short*)(ws);                 // 2MB frag-layout
  unsigned short* Kn   = (unsigned short*)(ws + (2u << 20));    // 2MB row-major
  unsigned short* ftf  = (unsigned short*)(ws + (4u << 20));    // 4MB frag-layout
  unsigned*       bits = (unsigned*)(ws + (8u << 20));          // 8MB bitmask
  float*          num_p = (float*)(ws + (16u << 20));           // 4 x 8MB
  float*          den_p = (float*)(ws + (48u << 20));           // 8 x 32KB
  if (ws_size < (48u << 20) + 262144u) return;                  // ~48.25MB scratch

  k_pack<<<16384, 256, 0, stream>>>(adj, bits);
  k_ftfrag<<<1024, 256, 0, stream>>>(feat, ftf);
  k_proj<<<128, 256, 0, stream>>>(feat, Wq, Wk, Qnf, Kn);
  k_attn<<<512, 256, 0, stream>>>(bits, Qnf, Kn, ftf, num_p, den_p);
  k_final<<<2048, 256, 0, stream>>>(num_p, den_p, feat, out);
}

// Round 7
// 193.210 us; speedup vs baseline: 1.4965x; 1.4965x over previous
//
#include <hip/hip_runtime.h>
#include <stdint.h>
#include <stddef.h>

#define NN 8192
#define DD 256
#define HH 128

typedef short bf16x8  __attribute__((ext_vector_type(8)));
typedef float f32x4   __attribute__((ext_vector_type(4)));
typedef float f32x16  __attribute__((ext_vector_type(16)));
typedef int   i32x4   __attribute__((ext_vector_type(4)));

// f32 -> bf16 RNE
static __device__ __forceinline__ short f2bf(float x){
  unsigned u = __float_as_uint(x);
  u = (u + 0x7FFFu + ((u >> 16) & 1u)) >> 16;
  return (short)(unsigned short)u;
}
static __device__ __forceinline__ bf16x8 cvt8(const float* p){
  f32x4 a = *(const f32x4*)p;
  f32x4 b = *(const f32x4*)(p + 4);
  bf16x8 o;
  o[0]=f2bf(a[0]); o[1]=f2bf(a[1]); o[2]=f2bf(a[2]); o[3]=f2bf(a[3]);
  o[4]=f2bf(b[0]); o[5]=f2bf(b[1]); o[6]=f2bf(b[2]); o[7]=f2bf(b[3]);
  return o;
}
static __device__ __forceinline__ bf16x8 ld16(const void* p){
  i32x4 v = *(const i32x4*)p;
  return __builtin_bit_cast(bf16x8, v);
}

// ---------- k_prep: ftfrag (all blocks) + projections (blocks 0-127) ----------
// ftf: MFMA B-frag layout: frag (jt=j>>4, dt=d>>5): elem (j,d) at
//   ((jt*8+dt)*64 + (d&31) + 32*((j>>3)&1))*8 + (j&7).
// Qnf: B-frag layout: elem (j,k) at ((j>>5)*8 + (k>>4))*512 + ((j&31)+32*((k>>3)&1))*8 + (k&7).
// Kn: row-major [i][128].
__global__ __launch_bounds__(256) void k_prep(const float* __restrict__ f,
                                              const float* __restrict__ Wq,
                                              const float* __restrict__ Wk,
                                              unsigned short* __restrict__ ftf,
                                              unsigned short* __restrict__ Qnf,
                                              unsigned short* __restrict__ Kn){
  __shared__ unsigned short wb[128][40];   // staged W chunk (pad 32->40: conflict-free reads)
  int t = threadIdx.x, l = t & 63;
  // ---- part A: feature fragments (every block: 4 frags) ----
  {
    int fr = blockIdx.x * 4 + (t >> 6);    // 0..4095
    int jt = fr >> 3, dt = fr & 7;
    int j = jt * 16 + (l >> 5) * 8, d = dt * 32 + (l & 31);
    bf16x8 o;
    #pragma unroll
    for (int e = 0; e < 8; ++e) o[e] = f2bf(f[(size_t)(j + e) * DD + d]);
    *(bf16x8*)(ftf + (size_t)fr * 512 + l * 8) = o;
  }
  if (blockIdx.x >= 128) return;
  // ---- part B: projections for rows i0..i0+63 ----
  int wave = t >> 6;
  int i0 = blockIdx.x * 64 + wave * 16;
  int lr = l & 15, lk = l >> 4;
  bf16x8 ka[8];
  #pragma unroll
  for (int ks = 0; ks < 8; ++ks)
    ka[ks] = cvt8(f + (size_t)(i0 + lr) * DD + ks * 32 + lk * 8);
  for (int pj = 0; pj < 2; ++pj){
    const float* W = pj ? Wk : Wq;
    f32x4 acc[8];
    #pragma unroll
    for (int n = 0; n < 8; ++n) acc[n] = (f32x4){0.f,0.f,0.f,0.f};
    for (int ks = 0; ks < 8; ++ks){
      // stage W[:,ks*32..+32) as bf16 in LDS (coalesced 1KB-row reads)
      __syncthreads();
      { int row = t >> 1, c0 = (t & 1) * 16;
        const float* wp = W + (size_t)row * DD + ks * 32 + c0;
        bf16x8 w0 = cvt8(wp), w1 = cvt8(wp + 8);
        *(bf16x8*)&wb[row][c0]     = w0;
        *(bf16x8*)&wb[row][c0 + 8] = w1; }
      __syncthreads();
      #pragma unroll
      for (int n = 0; n < 8; ++n){
        bf16x8 bb = ld16(&wb[n * 16 + lr][lk * 8]);
        acc[n] = __builtin_amdgcn_mfma_f32_16x16x32_bf16(ka[ks], bb, acc[n], 0, 0, 0);
      }
    }
    #pragma unroll
    for (int r = 0; r < 4; ++r){
      float n2 = 0.f;
      #pragma unroll
      for (int n = 0; n < 8; ++n){ float v = acc[n][r]; n2 += v * v; }
      n2 += __shfl_xor(n2, 1); n2 += __shfl_xor(n2, 2);
      n2 += __shfl_xor(n2, 4); n2 += __shfl_xor(n2, 8);
      float s = 1.f / fmaxf(sqrtf(n2), 1e-4f);   // torch cosine eps
      int row = i0 + lk * 4 + r;
      #pragma unroll
      for (int n = 0; n < 8; ++n){
        short v = f2bf(acc[n][r] * s);
        if (pj){
          Kn[(size_t)row * HH + n * 16 + lr] = (unsigned short)v;
        } else {
          size_t off = ((size_t)(row >> 5) * 8 + n) * 512
                     + ((row & 31) + 32 * (lr >> 3)) * 8 + (lr & 7);
          Qnf[off] = (unsigned short)v;
        }
      }
    }
  }
}

// ---------- fused masked-softmax attention (v7 = v5 core, prefetch-first) ----------
// 512 blocks = 128 ib x 4 js. 4 waves. Per 64-j step:
//  adj 64x64 tile coalesced (4 rows x 256B per dwordx4), double-buffered in LDS,
//  prefetch ISSUED FIRST in the step body (max latency cover before barrier drain);
//  QK^T (32x32x16, frag loads from L2) -> exp via LDS mask -> P via 8KB swizzled
//  LDS -> PV. adj read exactly once, nt (no L2 pollution of Qnf/ftf working set).
__global__ __launch_bounds__(256, 2) void k_attn(
      const int* __restrict__ adj,
      const unsigned short* __restrict__ Qnf, const unsigned short* __restrict__ Kn,
      const unsigned short* __restrict__ ftf,
      float* __restrict__ num_p, float* __restrict__ den_p){
  __shared__ __attribute__((aligned(16))) char p_lds[8192];       // P [64i][64j] bf16 swizzled
  __shared__ __attribute__((aligned(16))) int adj_lds[2][64][64]; // adj tiles, dbuf
  int t = threadIdx.x, wave = t >> 6, l = t & 63;
  int lc = l & 31, h = l >> 5;
  int ig = wave >> 1, jg = wave & 1, wq = wave;
  int ib = blockIdx.x >> 2, js = blockIdx.x & 3;
  int i0 = ib * 64;
  int jbase = js * 2048;

  // Kn A-frags: lane holds Kn[i0+ig*32+lc][hs*16 + h*8 + e]
  bf16x8 kb[8];
  { const unsigned short* kp = Kn + (size_t)(i0 + ig * 32 + lc) * HH + h * 8;
    #pragma unroll
    for (int hs = 0; hs < 8; ++hs) kb[hs] = ld16(kp + hs * 16); }

  f32x16 pv00, pv01, pv10, pv11;
  #pragma unroll
  for (int e = 0; e < 16; ++e){ pv00[e]=0.f; pv01[e]=0.f; pv10[e]=0.f; pv11[e]=0.f; }
  float dacc[16];
  #pragma unroll
  for (int r = 0; r < 16; ++r) dacc[r] = 0.f;

  // adj tile rows for this wave: wave*16 + k4*4 + (l>>4); cols (l&15)*4 (dwordx4)
  int arow = wave * 16 + (l >> 4);
  int acol = (l & 15) * 4;

  // prologue: stage adj step-0 tile
  #pragma unroll
  for (int k4 = 0; k4 < 4; ++k4){
    i32x4 v = __builtin_nontemporal_load(
        (const i32x4*)(adj + (size_t)(i0 + arow + k4 * 4) * NN + jbase + acol));
    *(i32x4*)&adj_lds[0][arow + k4 * 4][acol] = v;
  }
  __syncthreads();

  for (int s = 0; s < 32; ++s){
    int j0 = jbase + s * 64;
    int cur = s & 1, nxt = cur ^ 1;

    // issue adj prefetch for s+1 FIRST (earliest possible; consumed post-barrier1)
    i32x4 av[4];
    if (s < 31){
      #pragma unroll
      for (int k4 = 0; k4 < 4; ++k4)
        av[k4] = __builtin_nontemporal_load(
            (const i32x4*)(adj + (size_t)(i0 + arow + k4 * 4) * NN + j0 + 64 + acol));
    }

    // Qn frag loads (L2)
    bf16x8 qv[8];
    { const unsigned short* qb = Qnf + ((size_t)((j0 + jg * 32) >> 5) * 8) * 512 + (size_t)l * 8;
      #pragma unroll
      for (int hs = 0; hs < 8; ++hs) qv[hs] = ld16(qb + hs * 512); }

    // ft frag loads (L2)
    bf16x8 bv[8];
    { const unsigned short* fb = ftf + ((size_t)(j0 >> 4) * 8 + wq * 2) * 512 + (size_t)l * 8;
      #pragma unroll
      for (int ks = 0; ks < 4; ++ks){
        bv[ks * 2]     = ld16(fb + ks * 4096);
        bv[ks * 2 + 1] = ld16(fb + ks * 4096 + 512); } }

    // QK^T: st[r] = S[i0+ig*32 + (r&3)+8*(r>>2)+4h][j0 + jg*32 + lc]
    f32x16 st;
    #pragma unroll
    for (int e = 0; e < 16; ++e) st[e] = 0.f;
    #pragma unroll
    for (int hs = 0; hs < 8; ++hs)
      st = __builtin_amdgcn_mfma_f32_32x32x16_bf16(kb[hs], qv[hs], st, 0, 0, 0);

    // mask (LDS) -> exp -> P to swizzled LDS
    #pragma unroll
    for (int r = 0; r < 16; ++r){
      int row = ig * 32 + (r & 3) + 8 * (r >> 2) + 4 * h;
      int a = adj_lds[cur][row][jg * 32 + lc];
      float wv = (a > 0) ? __expf(st[r]) : 0.f;   // |s|<=1: exp safe, no max needed
      dacc[r] += wv;
      int byo = row * 128 + (((jg * 32 + lc) * 2) ^ ((row & 7) << 4));
      *(unsigned short*)(p_lds + byo) = (unsigned short)f2bf(wv);
    }
    __syncthreads();                     // barrier1: P visible

    // write prefetched adj tile to other buffer
    if (s < 31){
      #pragma unroll
      for (int k4 = 0; k4 < 4; ++k4)
        *(i32x4*)&adj_lds[nxt][arow + k4 * 4][acol] = av[k4];
    }

    // PV: pvXY += P(full 64j) * ft(d-quarter wq)
    #pragma unroll
    for (int ks = 0; ks < 4; ++ks){
      int ko = (ks * 32 + h * 16) ^ ((lc & 7) << 4);
      bf16x8 pa0 = ld16(p_lds + lc * 128 + ko);
      bf16x8 pa1 = ld16(p_lds + (32 + lc) * 128 + ko);
      pv00 = __builtin_amdgcn_mfma_f32_32x32x16_bf16(pa0, bv[ks*2],   pv00, 0,0,0);
      pv01 = __builtin_amdgcn_mfma_f32_32x32x16_bf16(pa0, bv[ks*2+1], pv01, 0,0,0);
      pv10 = __builtin_amdgcn_mfma_f32_32x32x16_bf16(pa1, bv[ks*2],   pv10, 0,0,0);
      pv11 = __builtin_amdgcn_mfma_f32_32x32x16_bf16(pa1, bv[ks*2+1], pv11, 0,0,0);
    }
    __syncthreads();                     // barrier2: PV done; adj_lds[nxt] visible
  }

  // den partials: reduce over j-lanes, store per (js,jg)
  #pragma unroll
  for (int r = 0; r < 16; ++r){
    float v = dacc[r];
    v += __shfl_xor(v, 1); v += __shfl_xor(v, 2); v += __shfl_xor(v, 4);
    v += __shfl_xor(v, 8); v += __shfl_xor(v, 16);
    if (lc == 0){
      int i = i0 + ig * 32 + (r & 3) + 8 * (r >> 2) + 4 * h;
      den_p[(size_t)(js * 2 + jg) * NN + i] = v;
    }
  }
  // num partials: plain coalesced stores (per-js region)
  float* np = num_p + (size_t)js * NN * DD;
  #pragma unroll
  for (int r = 0; r < 16; ++r){
    int i = i0 + (r & 3) + 8 * (r >> 2) + 4 * h;
    int d = wq * 64 + lc;
    np[(size_t)i * DD + d]             = pv00[r];
    np[(size_t)i * DD + d + 32]        = pv01[r];
    np[(size_t)(i + 32) * DD + d]      = pv10[r];
    np[(size_t)(i + 32) * DD + d + 32] = pv11[r];
  }
}

// ---------- finalize: sum partials; out = den>0 ? 0.5*num/den + 0.5*f : f ----------
__global__ __launch_bounds__(256) void k_final(const float* __restrict__ num_p,
                                               const float* __restrict__ den_p,
                                               const float* __restrict__ f,
                                               float* __restrict__ out){
  int gid = blockIdx.x * 256 + threadIdx.x;
  int i = gid >> 6;
  f32x4 nv = (f32x4){0.f,0.f,0.f,0.f};
  float dv = 0.f;
  #pragma unroll
  for (int s = 0; s < 4; ++s)
    nv += *(const f32x4*)(num_p + (size_t)s * NN * DD + (size_t)gid * 4);
  #pragma unroll
  for (int s = 0; s < 8; ++s)
    dv += den_p[(size_t)s * NN + i];
  f32x4 fv = *(const f32x4*)(f + (size_t)gid * 4);
  f32x4 o;
  if (dv > 0.f){
    float inv = 0.5f / dv;
    o = nv * inv + fv * 0.5f;
  } else {
    o = fv;   // no-neighbor row keeps features
  }
  *(f32x4*)(out + (size_t)gid * 4) = o;
}

extern "C" void kernel_launch(void* const* d_in, const int* in_sizes, int n_in,
                              void* d_out, int out_size, void* d_ws, size_t ws_size,
                              hipStream_t stream){
  (void)in_sizes; (void)n_in; (void)out_size;
  const float* feat = (const float*)d_in[0];
  const int*   adj  = (const int*)d_in[1];
  const float* Wq   = (const float*)d_in[2];
  const float* Wk   = (const float*)d_in[3];
  float* out = (float*)d_out;
  char* ws = (char*)d_ws;
  unsigned short* Qnf  = (unsigned short*)(ws);                 // 2MB frag-layout
  unsigned short* Kn   = (unsigned short*)(ws + (2u << 20));    // 2MB row-major
  unsigned short* ftf  = (unsigned short*)(ws + (4u << 20));    // 4MB frag-layout
  float*          num_p = (float*)(ws + (8u << 20));            // 4 x 8MB
  float*          den_p = (float*)(ws + (40u << 20));           // 8 x 32KB
  if (ws_size < (40u << 20) + 262144u) return;                  // ~40.25MB scratch

  k_prep<<<1024, 256, 0, stream>>>(feat, Wq, Wk, ftf, Qnf, Kn);
  k_attn<<<512, 256, 0, stream>>>(adj, Qnf, Kn, ftf, num_p, den_p);
  k_final<<<2048, 256, 0, stream>>>(num_p, den_p, feat, out);
}